// Round 5
// baseline (410.791 us; speedup 1.0000x reference)
//
#include <hip/hip_runtime.h>
#include <math.h>

#define S_LEN 4096
#define D_MODEL 2048
#define N_HEADS 16
#define N_KV 4
#define HEAD_DIM 128
#define KV_D 512
#define QKV_N 3072   // fused QKV projection width; Q/K row stride
#define SM_SHIFT 18.0f  // fixed softmax shift (log2 domain); exact identity

typedef short bf16x8 __attribute__((ext_vector_type(8)));
typedef float f32x4 __attribute__((ext_vector_type(4)));

#if __has_builtin(__builtin_amdgcn_exp2f)
#define EXP2(x) __builtin_amdgcn_exp2f(x)
#else
#define EXP2(x) exp2f(x)
#endif

// raw barrier with compiler memory ordering (no implicit full waitcnt drain)
#define SBAR() asm volatile("s_barrier" ::: "memory")
#define VMCNT(n) asm volatile("s_waitcnt vmcnt(" #n ")" ::: "memory")

static __device__ __forceinline__ float b2f(unsigned short h) {
  return __uint_as_float(((unsigned int)h) << 16);
}
// HW packed f32->bf16 (RNE): lo half = cvt(a), hi half = cvt(b). 1 instr vs ~7.
static __device__ __forceinline__ unsigned int cvt_pk_bf16(float a, float b) {
  unsigned int r;
  asm("v_cvt_pk_bf16_f32 %0, %1, %2" : "=v"(r) : "v"(a), "v"(b));
  return r;
}
// scalar f32->bf16 via the same HW op (RNE; identical numerics to manual RNE)
static __device__ __forceinline__ unsigned short f2b(float f) {
  return (unsigned short)cvt_pk_bf16(f, f);
}

// async 16B global -> LDS (wave-uniform base + lane*16 ordering)
static __device__ __forceinline__ void gload_lds16(const unsigned short* g,
                                                   unsigned short* l) {
  __builtin_amdgcn_global_load_lds(
      (const __attribute__((address_space(1))) void*)g,
      (__attribute__((address_space(3))) void*)l, 16, 0, 0);
}

// ---------------------------------------------------------------------------
// prep: blocks [0,4096) convert X fp32->bf16; remaining blocks transpose the
// four weight matrices into bf16 W^T form (Wq/Wk/Wv stacked [3072][2048]).
// ---------------------------------------------------------------------------
__global__ __launch_bounds__(256) void prep_kernel(
    const float* __restrict__ X, const float* __restrict__ Wq,
    const float* __restrict__ Wk, const float* __restrict__ Wv,
    const float* __restrict__ Wo, unsigned short* __restrict__ Xb,
    unsigned short* __restrict__ Wqkv, unsigned short* __restrict__ WoT) {
  __shared__ float tile[32][33];
  const int b = blockIdx.x, t = threadIdx.x;
  if (b < 4096) {  // convx: 2048 elems per block
    int i = b * 2048 + t * 8;
    float4 a = *(const float4*)(X + i);
    float4 v = *(const float4*)(X + i + 4);
    unsigned int tmp[4] = {cvt_pk_bf16(a.x, a.y), cvt_pk_bf16(a.z, a.w),
                           cvt_pk_bf16(v.x, v.y), cvt_pk_bf16(v.z, v.w)};
    *(uint4*)&Xb[i] = *(uint4*)tmp;
    return;
  }
  int id = b - 4096;
  const float* src;
  unsigned short* dst;
  int N, tc, rowOff;
  if (id < 4096) { src = Wq; dst = Wqkv; N = 2048; tc = 64; rowOff = 0; }
  else if (id < 5120) { id -= 4096; src = Wk; dst = Wqkv; N = 512; tc = 16; rowOff = 2048; }
  else if (id < 6144) { id -= 5120; src = Wv; dst = Wqkv; N = 512; tc = 16; rowOff = 2560; }
  else { id -= 6144; src = Wo; dst = WoT; N = 2048; tc = 64; rowOff = 0; }
  const int c0 = (id % tc) * 32, r0 = (id / tc) * 32;
  const int col = t & 31, rb = t >> 5;
#pragma unroll
  for (int i = 0; i < 4; i++)
    tile[rb + i * 8][col] = src[(size_t)(r0 + rb + i * 8) * N + c0 + col];
  __syncthreads();
#pragma unroll
  for (int i = 0; i < 4; i++)
    dst[(size_t)(rowOff + c0 + rb + i * 8) * 2048 + r0 + col] =
        f2b(tile[col][rb + i * 8]);
}

// ---------------------------------------------------------------------------
// Phase-split big-tile bf16 GEMM (T2+T3+T4+T5 stack, R5):
// C(M x N) = A(M x K) @ Bt(N x K)^T.  BM x 256 tile, BK=64, 512 thr = 8 waves
// (2M x 4N), per-wave output (BM/2) x 64, acc (BM/32) x 4 f32x4.
// - LDS double-buffered, chunk-XOR swizzle c^=(row&7) (full 8-deep; both-sides
//   involution: pre-swizzled global source + swizzled ds_read).
// - 4 phases per K-tile, each = one C-quadrant x K=64: {ds_read frags; SBAR;
//   setprio(1); MFMA cluster; setprio(0); SBAR}.
// - Counted vmcnt at tile boundary only (T4): wait own previous tile's LPT
//   loads; next tile's stay in flight. Never 0 mid-loop.
// - Stage tile t+2 into the just-consumed buffer after the last phase barrier
//   (all waves' reads retired: lgkm-before-MFMA-before-barrier).
// ---------------------------------------------------------------------------
template <int BM, int BF16OUT>
__global__ __launch_bounds__(512, 2) void gemm256_kernel(
    const unsigned short* __restrict__ A, const unsigned short* __restrict__ Bt,
    void* __restrict__ C, int N, int K) {
  constexpr int MT = BM / 32;   // per-wave M-fragments (8 or 4)
  constexpr int ALT = BM / 64;  // A staging loads per thread per tile (4 or 2)
  __shared__ unsigned short As[2][BM * 64];
  __shared__ unsigned short Bs[2][256 * 64];

  const int t = threadIdx.x;
  const int w = t >> 6, lane = t & 63;
  const int quad = lane >> 4, lx = lane & 15, lx7 = lx & 7;
  const int wave_m = w >> 2, wave_n = w & 3;
  const int row0 = blockIdx.y * BM, col0 = blockIdx.x * 256;

  // staging source pointers: LDS dest is lane-linear; source pre-swizzled by
  // the same involution the ds_read applies (chunk c -> c ^ (row&7)).
  const unsigned short* agp[ALT];
  const unsigned short* bgp[4];
#pragma unroll
  for (int j = 0; j < ALT; j++) {
    int ch = j * 512 + t;
    int r = ch >> 3, c = ch & 7;
    agp[j] = A + (size_t)(row0 + r) * K + ((c ^ (r & 7)) << 3);
  }
#pragma unroll
  for (int j = 0; j < 4; j++) {
    int ch = j * 512 + t;
    int r = ch >> 3, c = ch & 7;
    bgp[j] = Bt + (size_t)(col0 + r) * K + ((c ^ (r & 7)) << 3);
  }

  auto stage = [&](int kt, int b) {
#pragma unroll
    for (int j = 0; j < ALT; j++)
      gload_lds16(agp[j] + kt * 64, &As[b][(j * 512 + t) * 8]);
#pragma unroll
    for (int j = 0; j < 4; j++)
      gload_lds16(bgp[j] + kt * 64, &Bs[b][(j * 512 + t) * 8]);
  };

  f32x4 acc[MT][4];
#pragma unroll
  for (int mt = 0; mt < MT; mt++)
#pragma unroll
    for (int nt = 0; nt < 4; nt++) acc[mt][nt] = (f32x4){0.f, 0.f, 0.f, 0.f};

  const int NTK = K >> 6;
  stage(0, 0);
  stage(1, 1);

  for (int kt = 0; kt < NTK; kt++) {
    // boundary wait: own tile-kt loads landed; tile kt+1's stay in flight
    if (kt + 1 < NTK) {
      if constexpr (BM == 256) { VMCNT(8); } else { VMCNT(6); }
    } else {
      VMCNT(0);
    }
    SBAR();
    const unsigned short* AsC = As[kt & 1];
    const unsigned short* BsC = Bs[kt & 1];

#pragma unroll
    for (int ph = 0; ph < 4; ph++) {
      const int mq = ph >> 1, nq = ph & 1;
      bf16x8 af[MT / 2][2], bf[2][2];
#pragma unroll
      for (int mt = 0; mt < MT / 2; mt++)
#pragma unroll
        for (int ks = 0; ks < 2; ks++)
          af[mt][ks] = *(const bf16x8*)&AsC[
              (wave_m * (MT * 16) + (mq * (MT / 2) + mt) * 16 + lx) * 64 +
              (((ks * 4 + quad) ^ lx7) << 3)];
#pragma unroll
      for (int nt = 0; nt < 2; nt++)
#pragma unroll
        for (int ks = 0; ks < 2; ks++)
          bf[nt][ks] = *(const bf16x8*)&BsC[
              (wave_n * 64 + (nq * 2 + nt) * 16 + lx) * 64 +
              (((ks * 4 + quad) ^ lx7) << 3)];
      SBAR();  // phase lockstep: ds_read issue of one wave overlaps MFMA of others
      __builtin_amdgcn_s_setprio(1);
#pragma unroll
      for (int mt = 0; mt < MT / 2; mt++)
#pragma unroll
        for (int nt = 0; nt < 2; nt++)
#pragma unroll
          for (int ks = 0; ks < 2; ks++)
            acc[mq * (MT / 2) + mt][nq * 2 + nt] =
                __builtin_amdgcn_mfma_f32_16x16x32_bf16(
                    af[mt][ks], bf[nt][ks], acc[mq * (MT / 2) + mt][nq * 2 + nt],
                    0, 0, 0);
      __builtin_amdgcn_s_setprio(0);
      SBAR();  // all waves done reading this quadrant's frags before next phase
    }
    // stage t+2 into the buffer just consumed (all reads retired: each wave's
    // ds_reads complete before its MFMA (lgkm), MFMA before its last SBAR).
    if (kt + 2 < NTK) stage(kt + 2, kt & 1);
  }

  // epilogue: C row = A-row index, col = B-row index (verified mapping)
  if (BF16OUT) {
    unsigned short* Cp = (unsigned short*)C;
#pragma unroll
    for (int mt = 0; mt < MT; mt++)
#pragma unroll
      for (int nt = 0; nt < 4; nt++)
#pragma unroll
        for (int r = 0; r < 4; r++) {
          int row = row0 + wave_m * (MT * 16) + mt * 16 + quad * 4 + r;
          int col = col0 + wave_n * 64 + nt * 16 + lx;
          Cp[(size_t)row * N + col] = f2b(acc[mt][nt][r]);
        }
  } else {
    float* Cp = (float*)C;
#pragma unroll
    for (int mt = 0; mt < MT; mt++)
#pragma unroll
      for (int nt = 0; nt < 4; nt++)
#pragma unroll
        for (int r = 0; r < 4; r++) {
          int row = row0 + wave_m * (MT * 16) + mt * 16 + quad * 4 + r;
          int col = col0 + wave_n * 64 + nt * 16 + lx;
          Cp[(size_t)row * N + col] = acc[mt][nt][r];
        }
  }
}

// ---------------------------------------------------------------------------
// Merged RoPE + V-transpose (independent column ranges of QKV; one launch).
// Blocks [0, 20480): RoPE in place on QKV (row stride 3072). Q cols [0,2048)
// get the combined scale log2(e)/sqrt(HD); K cols [2048,2560) unscaled.
// Blocks [20480, 22528): transpose V (cols [2560,3072)) -> Vt (512 x S).
// ---------------------------------------------------------------------------
__global__ __launch_bounds__(256) void ropev_kernel(
    unsigned short* __restrict__ QKV, unsigned short* __restrict__ Vt) {
  const int t = threadIdx.x;
  if (blockIdx.x < 20480) {
    int id = blockIdx.x * 256 + t;
    int d = id & 63;
    int rem = id >> 6;
    int head = rem % 20;
    int s = rem / 20;
    unsigned short* p;
    float scale;
    if (head < N_HEADS) {
      p = QKV + (size_t)s * QKV_N + head * HEAD_DIM;
      scale = 0.12753139187f;  // log2(e) / sqrt(128)
    } else {
      p = QKV + (size_t)s * QKV_N + 2048 + (head - N_HEADS) * HEAD_DIM;
      scale = 1.0f;
    }
    float inv = exp2f(-(float)d * (13.287712379549449f / 64.0f));
    float ang = (float)s * inv;
    float sn, c;
    sincosf(ang, &sn, &c);
    float xr = b2f(p[d]), xi = b2f(p[d + 64]);
    p[d] = f2b((xr * c - xi * sn) * scale);
    p[d + 64] = f2b((xr * sn + xi * c) * scale);
    return;
  }
  __shared__ unsigned short tile[32][33];
  const unsigned short* Vb = QKV + 2560;
  int id = blockIdx.x - 20480;
  const int c0 = (id & 15) * 32;   // 512/32 = 16 column tiles
  const int s0 = (id >> 4) * 32;
  const int col = t & 31, rbase = t >> 5;
#pragma unroll
  for (int i = 0; i < 4; i++) {
    int row = rbase + i * 8;
    tile[row][col] = Vb[(size_t)(s0 + row) * QKV_N + c0 + col];
  }
  __syncthreads();
#pragma unroll
  for (int i = 0; i < 4; i++) {
    int row = rbase + i * 8;
    Vt[(size_t)(c0 + row) * S_LEN + s0 + col] = tile[col][row];
  }
}

// ---------------------------------------------------------------------------
// Flash attention, transposed-score form, FIXED-SHIFT softmax.
// (R4 state: counted-vmcnt split waits, setprio around MFMA, deferred
// l-reduction; 166 us, MfmaUtil 36 / VALU 30 / LDS ~55%, no pipe saturated
// at 2 waves/SIMD -- further micro-opts in the +-1-4% regime.)
// ---------------------------------------------------------------------------
__global__ __launch_bounds__(256, 2) void attn_kernel(
    const unsigned short* __restrict__ Qb, const unsigned short* __restrict__ Kb,
    const unsigned short* __restrict__ Vt, unsigned short* __restrict__ Ob) {
  __shared__ unsigned short Ks[2][64 * 128];   // [krow][d], chunk-swizzled
  __shared__ unsigned short Vs[2][128 * 64];   // [d][krow], chunk-swizzled
  __shared__ unsigned short Pt[4][32 * 64];    // per-wave P^T [q][k], swizzled

  const int t = threadIdx.x;
  const int wave = t >> 6;
  const int lane = t & 63;
  const int quad = lane >> 4;
  const int lx = lane & 15;
  const int lx7 = lx & 7;
  const int qt = blockIdx.x;   // 0..31
  const int h = blockIdx.y;    // 0..15
  const int kvh = h >> 2;

  const unsigned short* Kg = Kb + kvh * HEAD_DIM;              // stride QKV_N
  const unsigned short* Vg = Vt + (size_t)(kvh * HEAD_DIM) * S_LEN;

  // Q fragments (whole kernel in registers): B-operand [n=lx][k=quad*8+j]
  const unsigned short* Qg =
      Qb + (size_t)(qt * 128 + wave * 32) * QKV_N + h * HEAD_DIM;
  bf16x8 qf[2][4];
#pragma unroll
  for (int qs = 0; qs < 2; qs++)
#pragma unroll
    for (int ks = 0; ks < 4; ks++)
      qf[qs][ks] = *(const bf16x8*)(Qg + (size_t)(qs * 16 + lx) * QKV_N +
                                    (quad << 3) + (ks << 5));

  f32x4 oacc[2][8];
#pragma unroll
  for (int qs = 0; qs < 2; qs++)
#pragma unroll
    for (int dt = 0; dt < 8; dt++) oacc[qs][dt] = (f32x4){0.f, 0.f, 0.f, 0.f};
  float l_st[2] = {0.f, 0.f};

  // K tile: 64 rows x 16 chunks; slot(r,c) holds global chunk (r, c^(r&7)).
  // V^T tile: 128 rows x 8 chunks; same self-inverse XOR swizzle.
  const unsigned short* kgp[4];
  const unsigned short* vgp[4];
#pragma unroll
  for (int j = 0; j < 4; j++) {
    int ch = (j * 4 + wave) * 64 + lane;
    int r = ch >> 4, c = ch & 15;
    kgp[j] = Kg + (size_t)r * QKV_N + ((c ^ (r & 7)) << 3);
    int d = ch >> 3, c2 = ch & 7;
    vgp[j] = Vg + (size_t)d * S_LEN + ((c2 ^ (d & 7)) << 3);
  }

  // K loads issued before V loads: top-of-tile vmcnt(4) = own K landed;
  // mid-tile vmcnt(8) = own V landed (next-tile prefetch stays in flight).
  auto stage = [&](int kt, int b) {
#pragma unroll
    for (int j = 0; j < 4; j++) {  // 4 * 4 waves * 64 lanes = 1024 chunks
      int ch = (j * 4 + wave) * 64 + lane;
      gload_lds16(kgp[j] + (size_t)kt * (64 * QKV_N), &Ks[b][ch * 8]);
    }
#pragma unroll
    for (int j = 0; j < 4; j++) {
      int ch = (j * 4 + wave) * 64 + lane;
      gload_lds16(vgp[j] + kt * 64, &Vs[b][ch * 8]);
    }
  };

  stage(0, 0);

  for (int kt = 0; kt < S_LEN / 64; kt++) {
    VMCNT(4);   // own K(kt) landed (V may still be in flight)
    SBAR();     // all waves' K(kt) visible
    if (kt + 1 < S_LEN / 64) stage(kt + 1, (kt + 1) & 1);  // prefetch overlap
    const unsigned short* KsC = Ks[kt & 1];
    const unsigned short* VsC = Vs[kt & 1];

    // ---- S^T = K @ Q^T fused with exp2/store; acc seeded with -SM_SHIFT so
    // no per-element subtract: k = ksub*16+quad*4+r, q = qs*16+lx
#pragma unroll
    for (int ksub = 0; ksub < 4; ksub++) {
      bf16x8 kf[4];
#pragma unroll
      for (int ks = 0; ks < 4; ks++)
        kf[ks] = *(const bf16x8*)&KsC[(ksub * 16 + lx) * 128 +
                                      (((ks * 4 + quad) ^ lx7) << 3)];
#pragma unroll
      for (int qs = 0; qs < 2; qs++) {
        f32x4 a = (f32x4){-SM_SHIFT, -SM_SHIFT, -SM_SHIFT, -SM_SHIFT};
        __builtin_amdgcn_s_setprio(1);
#pragma unroll
        for (int ks = 0; ks < 4; ks++)
          a = __builtin_amdgcn_mfma_f32_16x16x32_bf16(kf[ks], qf[qs][ks], a, 0, 0, 0);
        __builtin_amdgcn_s_setprio(0);
        float p0 = EXP2(a[0]);
        float p1 = EXP2(a[1]);
        float p2 = EXP2(a[2]);
        float p3 = EXP2(a[3]);
        l_st[qs] += (p0 + p1) + (p2 + p3);
        // P^T[q][k]: k = ksub*16+quad*4 (+r); chunk 2ksub+(quad>>1) ^ lx7
        *(uint2*)&Pt[wave][(qs * 16 + lx) * 64 +
                           (((2 * ksub + (quad >> 1)) ^ lx7) << 3) +
                           ((quad & 1) << 2)] =
            make_uint2(cvt_pk_bf16(p0, p1), cvt_pk_bf16(p2, p3));
      }
    }

    // ---- wait own V(kt) landed; next-tile prefetch (8 loads) stays live ----
    if (kt + 1 < S_LEN / 64) { VMCNT(8); } else { VMCNT(0); }
    SBAR();     // all waves' V(kt) visible

    // ---- O^T += V^T @ P^T (Pt wave-local: lgkm wait only) ----
#pragma unroll
    for (int st = 0; st < 2; st++) {
      const int pc = ((st * 4 + quad) ^ lx7) << 3;
      bf16x8 pb0 = *(const bf16x8*)&Pt[wave][lx * 64 + pc];
      bf16x8 pb1 = *(const bf16x8*)&Pt[wave][(16 + lx) * 64 + pc];
      __builtin_amdgcn_s_setprio(1);
#pragma unroll
      for (int dt = 0; dt < 8; dt++) {
        bf16x8 vf = *(const bf16x8*)&VsC[(dt * 16 + lx) * 64 + pc];
        oacc[0][dt] = __builtin_amdgcn_mfma_f32_16x16x32_bf16(vf, pb0, oacc[0][dt], 0, 0, 0);
        oacc[1][dt] = __builtin_amdgcn_mfma_f32_16x16x32_bf16(vf, pb1, oacc[1][dt], 0, 0, 0);
      }
      __builtin_amdgcn_s_setprio(0);
    }
  }

  // ---- epilogue: final cross-lane l reduce, O = (O^T)^T / l, 8B stores ----
#pragma unroll
  for (int qs = 0; qs < 2; qs++) {
    float l = l_st[qs];
    l += __shfl_xor(l, 16);
    l += __shfl_xor(l, 32);
    float linv = 1.0f / l;
    unsigned short* ob = Ob +
        (size_t)(qt * 128 + wave * 32 + qs * 16 + lx) * D_MODEL + h * HEAD_DIM +
        quad * 4;
#pragma unroll
    for (int dt = 0; dt < 8; dt++) {
      *(uint2*)&ob[dt * 16] = make_uint2(
          cvt_pk_bf16(oacc[qs][dt][0] * linv, oacc[qs][dt][1] * linv),
          cvt_pk_bf16(oacc[qs][dt][2] * linv, oacc[qs][dt][3] * linv));
    }
  }
}

// ---------------------------------------------------------------------------
extern "C" void kernel_launch(void* const* d_in, const int* in_sizes, int n_in,
                              void* d_out, int out_size, void* d_ws,
                              size_t ws_size, hipStream_t stream) {
  const float* X = (const float*)d_in[0];   // 4096 x 2048
  const float* Wq = (const float*)d_in[1];  // 2048 x 2048
  const float* Wk = (const float*)d_in[2];  // 2048 x 512
  const float* Wv = (const float*)d_in[3];  // 2048 x 512
  const float* Wo = (const float*)d_in[4];  // 2048 x 2048
  float* out = (float*)d_out;               // 4096 x 2048

  const size_t MB = 1048576;
  char* ws = (char*)d_ws;
  unsigned short* Xb    = (unsigned short*)ws;              // 16 MB
  unsigned short* WqkvT = (unsigned short*)(ws + 16 * MB);  // 12 MB [3072][2048]
  unsigned short* WoT   = (unsigned short*)(ws + 28 * MB);  //  8 MB
  unsigned short* QKV   = (unsigned short*)(ws + 36 * MB);  // 24 MB [4096][3072]
  unsigned short* Vtr   = (unsigned short*)(ws + 60 * MB);  //  4 MB [512][4096]
  unsigned short* Ob    = (unsigned short*)(ws + 64 * MB);  // 16 MB

  dim3 blk(256);
  // prep: X conversion + all 4 weight transposes in one launch
  prep_kernel<<<14336, blk, 0, stream>>>(X, Wq, Wk, Wv, Wo, Xb, WqkvT, WoT);
  // fused QKV projection: [4096][3072] bf16; 256x256 tile -> 12x16 = 192 wgs
  gemm256_kernel<256, 1><<<dim3(QKV_N / 256, S_LEN / 256), dim3(512), 0, stream>>>(
      Xb, WqkvT, QKV, QKV_N, D_MODEL);
  // RoPE on Q (log2e-scaled) and K + V transpose -> Vt, one launch
  ropev_kernel<<<20480 + 2048, blk, 0, stream>>>(QKV, Vtr);
  // attention (bf16 MFMA, 32 q/wave, fixed-shift softmax), bf16 O
  attn_kernel<<<dim3(S_LEN / 128, N_HEADS), blk, 0, stream>>>(
      QKV, QKV + 2048, Vtr, Ob);
  // output projection (fp32 out): 128x256 tile -> 8x32 = 256 wgs (1/CU exact)
  gemm256_kernel<128, 0><<<dim3(D_MODEL / 256, S_LEN / 128), dim3(512), 0, stream>>>(
      Ob, WoT, out, D_MODEL, D_MODEL);
}

// Round 6
// 388.458 us; speedup vs baseline: 1.0575x; 1.0575x over previous
//
#include <hip/hip_runtime.h>
#include <math.h>

#define S_LEN 4096
#define D_MODEL 2048
#define N_HEADS 16
#define N_KV 4
#define HEAD_DIM 128
#define KV_D 512
#define QKV_N 3072   // fused QKV projection width; Q/K row stride
#define SM_SHIFT 18.0f  // fixed softmax shift (log2 domain); exact identity

typedef short bf16x8 __attribute__((ext_vector_type(8)));
typedef float f32x4 __attribute__((ext_vector_type(4)));

#if __has_builtin(__builtin_amdgcn_exp2f)
#define EXP2(x) __builtin_amdgcn_exp2f(x)
#else
#define EXP2(x) exp2f(x)
#endif

// raw barrier with compiler memory ordering (no implicit full waitcnt drain)
#define SBAR() asm volatile("s_barrier" ::: "memory")
#define VMCNT(n) asm volatile("s_waitcnt vmcnt(" #n ")" ::: "memory")

static __device__ __forceinline__ float b2f(unsigned short h) {
  return __uint_as_float(((unsigned int)h) << 16);
}
// HW packed f32->bf16 (RNE): lo half = cvt(a), hi half = cvt(b). 1 instr vs ~7.
static __device__ __forceinline__ unsigned int cvt_pk_bf16(float a, float b) {
  unsigned int r;
  asm("v_cvt_pk_bf16_f32 %0, %1, %2" : "=v"(r) : "v"(a), "v"(b));
  return r;
}
// scalar f32->bf16 via the same HW op (RNE; identical numerics to manual RNE)
static __device__ __forceinline__ unsigned short f2b(float f) {
  return (unsigned short)cvt_pk_bf16(f, f);
}

// async 16B global -> LDS (wave-uniform base + lane*16 ordering)
static __device__ __forceinline__ void gload_lds16(const unsigned short* g,
                                                   unsigned short* l) {
  __builtin_amdgcn_global_load_lds(
      (const __attribute__((address_space(1))) void*)g,
      (__attribute__((address_space(3))) void*)l, 16, 0, 0);
}

// ---------------------------------------------------------------------------
// prep: blocks [0,4096) convert X fp32->bf16; remaining blocks transpose the
// four weight matrices into bf16 W^T form (Wq/Wk/Wv stacked [3072][2048]).
// ---------------------------------------------------------------------------
__global__ __launch_bounds__(256) void prep_kernel(
    const float* __restrict__ X, const float* __restrict__ Wq,
    const float* __restrict__ Wk, const float* __restrict__ Wv,
    const float* __restrict__ Wo, unsigned short* __restrict__ Xb,
    unsigned short* __restrict__ Wqkv, unsigned short* __restrict__ WoT) {
  __shared__ float tile[32][33];
  const int b = blockIdx.x, t = threadIdx.x;
  if (b < 4096) {  // convx: 2048 elems per block
    int i = b * 2048 + t * 8;
    float4 a = *(const float4*)(X + i);
    float4 v = *(const float4*)(X + i + 4);
    unsigned int tmp[4] = {cvt_pk_bf16(a.x, a.y), cvt_pk_bf16(a.z, a.w),
                           cvt_pk_bf16(v.x, v.y), cvt_pk_bf16(v.z, v.w)};
    *(uint4*)&Xb[i] = *(uint4*)tmp;
    return;
  }
  int id = b - 4096;
  const float* src;
  unsigned short* dst;
  int N, tc, rowOff;
  if (id < 4096) { src = Wq; dst = Wqkv; N = 2048; tc = 64; rowOff = 0; }
  else if (id < 5120) { id -= 4096; src = Wk; dst = Wqkv; N = 512; tc = 16; rowOff = 2048; }
  else if (id < 6144) { id -= 5120; src = Wv; dst = Wqkv; N = 512; tc = 16; rowOff = 2560; }
  else { id -= 6144; src = Wo; dst = WoT; N = 2048; tc = 64; rowOff = 0; }
  const int c0 = (id % tc) * 32, r0 = (id / tc) * 32;
  const int col = t & 31, rb = t >> 5;
#pragma unroll
  for (int i = 0; i < 4; i++)
    tile[rb + i * 8][col] = src[(size_t)(r0 + rb + i * 8) * N + c0 + col];
  __syncthreads();
#pragma unroll
  for (int i = 0; i < 4; i++)
    dst[(size_t)(rowOff + c0 + rb + i * 8) * 2048 + r0 + col] =
        f2b(tile[col][rb + i * 8]);
}

// ---------------------------------------------------------------------------
// bf16 MFMA GEMM (m97 structure, R6: + XCD-aware block swizzle T1):
// C(MxN) = A(MxK) @ Bt(NxK)^T. 128x128 tile, BK=32, 256 thr = 4 waves,
// global_load_lds staging. Grid must be divisible by 8 (768 and 512 here):
// remap so each XCD owns a contiguous tile range -> A-panel slice (~2MB)
// becomes L2-resident instead of round-robin re-fetch.
// ---------------------------------------------------------------------------
__global__ __launch_bounds__(256) void bgemm_kernel(
    const unsigned short* __restrict__ A, const unsigned short* __restrict__ Bt,
    void* __restrict__ C, int M, int N, int K, int bf16_out) {
  __shared__ unsigned short As[128 * 32];
  __shared__ unsigned short Bs[128 * 32];

  const int t = threadIdx.x;
  const int w = t >> 6, l = t & 63;
  const int quad = l >> 4, lx = l & 15;

  // T1 XCD swizzle (bijective: nwg % 8 == 0 for both call sites)
  const int nwg = gridDim.x * gridDim.y;
  const int orig = blockIdx.y * gridDim.x + blockIdx.x;
  const int swz = (orig & 7) * (nwg >> 3) + (orig >> 3);
  const int bx = swz % gridDim.x, by = swz / gridDim.x;
  const int row0 = by * 128, col0 = bx * 128;
  const int wr = (w >> 1) * 64, wc = (w & 1) * 64;

  f32x4 acc[4][4];
#pragma unroll
  for (int mt = 0; mt < 4; mt++)
#pragma unroll
    for (int nt = 0; nt < 4; nt++) acc[mt][nt] = (f32x4){0.f, 0.f, 0.f, 0.f};

  for (int kt = 0; kt < K; kt += 32) {
    __syncthreads();
#pragma unroll
    for (int j = 0; j < 2; j++) {
      int ch = w * 128 + j * 64 + l;
      int r = ch >> 2, kc = (ch & 3) * 8;
      gload_lds16(A + (size_t)(row0 + r) * K + kt + kc, &As[ch * 8]);
      gload_lds16(Bt + (size_t)(col0 + r) * K + kt + kc, &Bs[ch * 8]);
    }
    __syncthreads();

    bf16x8 af[4], bfr[4];
#pragma unroll
    for (int mt = 0; mt < 4; mt++)
      af[mt] = *(const bf16x8*)&As[(wr + mt * 16 + lx) * 32 + quad * 8];
#pragma unroll
    for (int nt = 0; nt < 4; nt++)
      bfr[nt] = *(const bf16x8*)&Bs[(wc + nt * 16 + lx) * 32 + quad * 8];
#pragma unroll
    for (int mt = 0; mt < 4; mt++)
#pragma unroll
      for (int nt = 0; nt < 4; nt++)
        acc[mt][nt] = __builtin_amdgcn_mfma_f32_16x16x32_bf16(af[mt], bfr[nt],
                                                              acc[mt][nt], 0, 0, 0);
  }

  if (bf16_out) {
    unsigned short* Cp = (unsigned short*)C;
#pragma unroll
    for (int mt = 0; mt < 4; mt++)
#pragma unroll
      for (int nt = 0; nt < 4; nt++)
#pragma unroll
        for (int r = 0; r < 4; r++) {
          int row = row0 + wr + mt * 16 + quad * 4 + r;
          int col = col0 + wc + nt * 16 + lx;
          Cp[(size_t)row * N + col] = f2b(acc[mt][nt][r]);
        }
  } else {
    float* Cp = (float*)C;
#pragma unroll
    for (int mt = 0; mt < 4; mt++)
#pragma unroll
      for (int nt = 0; nt < 4; nt++)
#pragma unroll
        for (int r = 0; r < 4; r++) {
          int row = row0 + wr + mt * 16 + quad * 4 + r;
          int col = col0 + wc + nt * 16 + lx;
          Cp[(size_t)row * N + col] = acc[mt][nt][r];
        }
  }
}

// ---------------------------------------------------------------------------
// Merged RoPE + V-transpose (independent column ranges of QKV; one launch).
// Blocks [0, 20480): RoPE in place on QKV (row stride 3072). Q cols [0,2048)
// get the combined scale log2(e)/sqrt(HD); K cols [2048,2560) unscaled.
// Blocks [20480, 22528): transpose V (cols [2560,3072)) -> Vt (512 x S).
// ---------------------------------------------------------------------------
__global__ __launch_bounds__(256) void ropev_kernel(
    unsigned short* __restrict__ QKV, unsigned short* __restrict__ Vt) {
  const int t = threadIdx.x;
  if (blockIdx.x < 20480) {
    int id = blockIdx.x * 256 + t;
    int d = id & 63;
    int rem = id >> 6;
    int head = rem % 20;
    int s = rem / 20;
    unsigned short* p;
    float scale;
    if (head < N_HEADS) {
      p = QKV + (size_t)s * QKV_N + head * HEAD_DIM;
      scale = 0.12753139187f;  // log2(e) / sqrt(128)
    } else {
      p = QKV + (size_t)s * QKV_N + 2048 + (head - N_HEADS) * HEAD_DIM;
      scale = 1.0f;
    }
    float inv = exp2f(-(float)d * (13.287712379549449f / 64.0f));
    float ang = (float)s * inv;
    float sn, c;
    sincosf(ang, &sn, &c);
    float xr = b2f(p[d]), xi = b2f(p[d + 64]);
    p[d] = f2b((xr * c - xi * sn) * scale);
    p[d + 64] = f2b((xr * sn + xi * c) * scale);
    return;
  }
  __shared__ unsigned short tile[32][33];
  const unsigned short* Vb = QKV + 2560;
  int id = blockIdx.x - 20480;
  const int c0 = (id & 15) * 32;   // 512/32 = 16 column tiles
  const int s0 = (id >> 4) * 32;
  const int col = t & 31, rbase = t >> 5;
#pragma unroll
  for (int i = 0; i < 4; i++) {
    int row = rbase + i * 8;
    tile[row][col] = Vb[(size_t)(s0 + row) * QKV_N + c0 + col];
  }
  __syncthreads();
#pragma unroll
  for (int i = 0; i < 4; i++) {
    int row = rbase + i * 8;
    Vt[(size_t)(c0 + row) * S_LEN + s0 + col] = tile[col][row];
  }
}

// ---------------------------------------------------------------------------
// Flash attention, transposed-score form, FIXED-SHIFT softmax.
// (R4 state: counted-vmcnt split waits, setprio around MFMA, deferred
// l-reduction; 165 us, MfmaUtil 36 / VALU 30, 2 waves/SIMD -- at this
// structure's plateau; further gains need a verified occupancy bump.)
// ---------------------------------------------------------------------------
__global__ __launch_bounds__(256, 2) void attn_kernel(
    const unsigned short* __restrict__ Qb, const unsigned short* __restrict__ Kb,
    const unsigned short* __restrict__ Vt, unsigned short* __restrict__ Ob) {
  __shared__ unsigned short Ks[2][64 * 128];   // [krow][d], chunk-swizzled
  __shared__ unsigned short Vs[2][128 * 64];   // [d][krow], chunk-swizzled
  __shared__ unsigned short Pt[4][32 * 64];    // per-wave P^T [q][k], swizzled

  const int t = threadIdx.x;
  const int wave = t >> 6;
  const int lane = t & 63;
  const int quad = lane >> 4;
  const int lx = lane & 15;
  const int lx7 = lx & 7;
  const int qt = blockIdx.x;   // 0..31
  const int h = blockIdx.y;    // 0..15
  const int kvh = h >> 2;

  const unsigned short* Kg = Kb + kvh * HEAD_DIM;              // stride QKV_N
  const unsigned short* Vg = Vt + (size_t)(kvh * HEAD_DIM) * S_LEN;

  // Q fragments (whole kernel in registers): B-operand [n=lx][k=quad*8+j]
  const unsigned short* Qg =
      Qb + (size_t)(qt * 128 + wave * 32) * QKV_N + h * HEAD_DIM;
  bf16x8 qf[2][4];
#pragma unroll
  for (int qs = 0; qs < 2; qs++)
#pragma unroll
    for (int ks = 0; ks < 4; ks++)
      qf[qs][ks] = *(const bf16x8*)(Qg + (size_t)(qs * 16 + lx) * QKV_N +
                                    (quad << 3) + (ks << 5));

  f32x4 oacc[2][8];
#pragma unroll
  for (int qs = 0; qs < 2; qs++)
#pragma unroll
    for (int dt = 0; dt < 8; dt++) oacc[qs][dt] = (f32x4){0.f, 0.f, 0.f, 0.f};
  float l_st[2] = {0.f, 0.f};

  // K tile: 64 rows x 16 chunks; slot(r,c) holds global chunk (r, c^(r&7)).
  // V^T tile: 128 rows x 8 chunks; same self-inverse XOR swizzle.
  const unsigned short* kgp[4];
  const unsigned short* vgp[4];
#pragma unroll
  for (int j = 0; j < 4; j++) {
    int ch = (j * 4 + wave) * 64 + lane;
    int r = ch >> 4, c = ch & 15;
    kgp[j] = Kg + (size_t)r * QKV_N + ((c ^ (r & 7)) << 3);
    int d = ch >> 3, c2 = ch & 7;
    vgp[j] = Vg + (size_t)d * S_LEN + ((c2 ^ (d & 7)) << 3);
  }

  // K loads issued before V loads: top-of-tile vmcnt(4) = own K landed;
  // mid-tile vmcnt(8) = own V landed (next-tile prefetch stays in flight).
  auto stage = [&](int kt, int b) {
#pragma unroll
    for (int j = 0; j < 4; j++) {  // 4 * 4 waves * 64 lanes = 1024 chunks
      int ch = (j * 4 + wave) * 64 + lane;
      gload_lds16(kgp[j] + (size_t)kt * (64 * QKV_N), &Ks[b][ch * 8]);
    }
#pragma unroll
    for (int j = 0; j < 4; j++) {
      int ch = (j * 4 + wave) * 64 + lane;
      gload_lds16(vgp[j] + kt * 64, &Vs[b][ch * 8]);
    }
  };

  stage(0, 0);

  for (int kt = 0; kt < S_LEN / 64; kt++) {
    VMCNT(4);   // own K(kt) landed (V may still be in flight)
    SBAR();     // all waves' K(kt) visible
    if (kt + 1 < S_LEN / 64) stage(kt + 1, (kt + 1) & 1);  // prefetch overlap
    const unsigned short* KsC = Ks[kt & 1];
    const unsigned short* VsC = Vs[kt & 1];

    // ---- S^T = K @ Q^T fused with exp2/store; acc seeded with -SM_SHIFT so
    // no per-element subtract: k = ksub*16+quad*4+r, q = qs*16+lx
#pragma unroll
    for (int ksub = 0; ksub < 4; ksub++) {
      bf16x8 kf[4];
#pragma unroll
      for (int ks = 0; ks < 4; ks++)
        kf[ks] = *(const bf16x8*)&KsC[(ksub * 16 + lx) * 128 +
                                      (((ks * 4 + quad) ^ lx7) << 3)];
#pragma unroll
      for (int qs = 0; qs < 2; qs++) {
        f32x4 a = (f32x4){-SM_SHIFT, -SM_SHIFT, -SM_SHIFT, -SM_SHIFT};
        __builtin_amdgcn_s_setprio(1);
#pragma unroll
        for (int ks = 0; ks < 4; ks++)
          a = __builtin_amdgcn_mfma_f32_16x16x32_bf16(kf[ks], qf[qs][ks], a, 0, 0, 0);
        __builtin_amdgcn_s_setprio(0);
        float p0 = EXP2(a[0]);
        float p1 = EXP2(a[1]);
        float p2 = EXP2(a[2]);
        float p3 = EXP2(a[3]);
        l_st[qs] += (p0 + p1) + (p2 + p3);
        // P^T[q][k]: k = ksub*16+quad*4 (+r); chunk 2ksub+(quad>>1) ^ lx7
        *(uint2*)&Pt[wave][(qs * 16 + lx) * 64 +
                           (((2 * ksub + (quad >> 1)) ^ lx7) << 3) +
                           ((quad & 1) << 2)] =
            make_uint2(cvt_pk_bf16(p0, p1), cvt_pk_bf16(p2, p3));
      }
    }

    // ---- wait own V(kt) landed; next-tile prefetch (8 loads) stays live ----
    if (kt + 1 < S_LEN / 64) { VMCNT(8); } else { VMCNT(0); }
    SBAR();     // all waves' V(kt) visible

    // ---- O^T += V^T @ P^T (Pt wave-local: lgkm wait only) ----
#pragma unroll
    for (int st = 0; st < 2; st++) {
      const int pc = ((st * 4 + quad) ^ lx7) << 3;
      bf16x8 pb0 = *(const bf16x8*)&Pt[wave][lx * 64 + pc];
      bf16x8 pb1 = *(const bf16x8*)&Pt[wave][(16 + lx) * 64 + pc];
      __builtin_amdgcn_s_setprio(1);
#pragma unroll
      for (int dt = 0; dt < 8; dt++) {
        bf16x8 vf = *(const bf16x8*)&VsC[(dt * 16 + lx) * 64 + pc];
        oacc[0][dt] = __builtin_amdgcn_mfma_f32_16x16x32_bf16(vf, pb0, oacc[0][dt], 0, 0, 0);
        oacc[1][dt] = __builtin_amdgcn_mfma_f32_16x16x32_bf16(vf, pb1, oacc[1][dt], 0, 0, 0);
      }
      __builtin_amdgcn_s_setprio(0);
    }
  }

  // ---- epilogue: final cross-lane l reduce, O = (O^T)^T / l, 8B stores ----
#pragma unroll
  for (int qs = 0; qs < 2; qs++) {
    float l = l_st[qs];
    l += __shfl_xor(l, 16);
    l += __shfl_xor(l, 32);
    float linv = 1.0f / l;
    unsigned short* ob = Ob +
        (size_t)(qt * 128 + wave * 32 + qs * 16 + lx) * D_MODEL + h * HEAD_DIM +
        quad * 4;
#pragma unroll
    for (int dt = 0; dt < 8; dt++) {
      *(uint2*)&ob[dt * 16] = make_uint2(
          cvt_pk_bf16(oacc[qs][dt][0] * linv, oacc[qs][dt][1] * linv),
          cvt_pk_bf16(oacc[qs][dt][2] * linv, oacc[qs][dt][3] * linv));
    }
  }
}

// ---------------------------------------------------------------------------
extern "C" void kernel_launch(void* const* d_in, const int* in_sizes, int n_in,
                              void* d_out, int out_size, void* d_ws,
                              size_t ws_size, hipStream_t stream) {
  const float* X = (const float*)d_in[0];   // 4096 x 2048
  const float* Wq = (const float*)d_in[1];  // 2048 x 2048
  const float* Wk = (const float*)d_in[2];  // 2048 x 512
  const float* Wv = (const float*)d_in[3];  // 2048 x 512
  const float* Wo = (const float*)d_in[4];  // 2048 x 2048
  float* out = (float*)d_out;               // 4096 x 2048

  const size_t MB = 1048576;
  char* ws = (char*)d_ws;
  unsigned short* Xb    = (unsigned short*)ws;              // 16 MB
  unsigned short* WqkvT = (unsigned short*)(ws + 16 * MB);  // 12 MB [3072][2048]
  unsigned short* WoT   = (unsigned short*)(ws + 28 * MB);  //  8 MB
  unsigned short* QKV   = (unsigned short*)(ws + 36 * MB);  // 24 MB [4096][3072]
  unsigned short* Vtr   = (unsigned short*)(ws + 60 * MB);  //  4 MB [512][4096]
  unsigned short* Ob    = (unsigned short*)(ws + 64 * MB);  // 16 MB

  dim3 blk(256);
  // prep: X conversion + all 4 weight transposes in one launch
  prep_kernel<<<14336, blk, 0, stream>>>(X, Wq, Wk, Wv, Wo, Xb, WqkvT, WoT);
  // fused QKV projection: [4096][3072] bf16 (768 wgs, %8==0 for swizzle)
  bgemm_kernel<<<dim3(QKV_N / 128, S_LEN / 128), blk, 0, stream>>>(
      Xb, WqkvT, QKV, S_LEN, QKV_N, D_MODEL, 1);
  // RoPE on Q (log2e-scaled) and K + V transpose -> Vt, one launch
  ropev_kernel<<<20480 + 2048, blk, 0, stream>>>(QKV, Vtr);
  // attention (bf16 MFMA, 32 q/wave, fixed-shift softmax), bf16 O
  attn_kernel<<<dim3(S_LEN / 128, N_HEADS), blk, 0, stream>>>(
      QKV, QKV + 2048, Vtr, Ob);
  // output projection (fp32 out): 512 wgs, %8==0 for swizzle
  bgemm_kernel<<<dim3(D_MODEL / 128, S_LEN / 128), blk, 0, stream>>>(
      Ob, WoT, out, S_LEN, D_MODEL, D_MODEL, 0);
}

// Round 7
// 386.982 us; speedup vs baseline: 1.0615x; 1.0038x over previous
//
#include <hip/hip_runtime.h>
#include <math.h>

#define S_LEN 4096
#define D_MODEL 2048
#define N_HEADS 16
#define N_KV 4
#define HEAD_DIM 128
#define KV_D 512
#define QKV_N 3072   // fused QKV projection width; Q/K row stride
#define SM_SHIFT 18.0f  // fixed softmax shift (log2 domain); exact identity

typedef short bf16x8 __attribute__((ext_vector_type(8)));
typedef float f32x4 __attribute__((ext_vector_type(4)));

#if __has_builtin(__builtin_amdgcn_exp2f)
#define EXP2(x) __builtin_amdgcn_exp2f(x)
#else
#define EXP2(x) exp2f(x)
#endif

// raw barrier with compiler memory ordering (no implicit full waitcnt drain)
#define SBAR() asm volatile("s_barrier" ::: "memory")
#define VMCNT(n) asm volatile("s_waitcnt vmcnt(" #n ")" ::: "memory")

static __device__ __forceinline__ float b2f(unsigned short h) {
  return __uint_as_float(((unsigned int)h) << 16);
}
// HW packed f32->bf16 (RNE): lo half = cvt(a), hi half = cvt(b). 1 instr vs ~7.
static __device__ __forceinline__ unsigned int cvt_pk_bf16(float a, float b) {
  unsigned int r;
  asm("v_cvt_pk_bf16_f32 %0, %1, %2" : "=v"(r) : "v"(a), "v"(b));
  return r;
}
// scalar f32->bf16 via the same HW op (RNE; identical numerics to manual RNE)
static __device__ __forceinline__ unsigned short f2b(float f) {
  return (unsigned short)cvt_pk_bf16(f, f);
}

// async 16B global -> LDS (wave-uniform base + lane*16 ordering)
static __device__ __forceinline__ void gload_lds16(const unsigned short* g,
                                                   unsigned short* l) {
  __builtin_amdgcn_global_load_lds(
      (const __attribute__((address_space(1))) void*)g,
      (__attribute__((address_space(3))) void*)l, 16, 0, 0);
}

// ---------------------------------------------------------------------------
// prep: blocks [0,4096) convert X fp32->bf16; remaining blocks transpose the
// four weight matrices into bf16 W^T form (Wq/Wk/Wv stacked [3072][2048]).
// ---------------------------------------------------------------------------
__global__ __launch_bounds__(256) void prep_kernel(
    const float* __restrict__ X, const float* __restrict__ Wq,
    const float* __restrict__ Wk, const float* __restrict__ Wv,
    const float* __restrict__ Wo, unsigned short* __restrict__ Xb,
    unsigned short* __restrict__ Wqkv, unsigned short* __restrict__ WoT) {
  __shared__ float tile[32][33];
  const int b = blockIdx.x, t = threadIdx.x;
  if (b < 4096) {  // convx: 2048 elems per block
    int i = b * 2048 + t * 8;
    float4 a = *(const float4*)(X + i);
    float4 v = *(const float4*)(X + i + 4);
    unsigned int tmp[4] = {cvt_pk_bf16(a.x, a.y), cvt_pk_bf16(a.z, a.w),
                           cvt_pk_bf16(v.x, v.y), cvt_pk_bf16(v.z, v.w)};
    *(uint4*)&Xb[i] = *(uint4*)tmp;
    return;
  }
  int id = b - 4096;
  const float* src;
  unsigned short* dst;
  int N, tc, rowOff;
  if (id < 4096) { src = Wq; dst = Wqkv; N = 2048; tc = 64; rowOff = 0; }
  else if (id < 5120) { id -= 4096; src = Wk; dst = Wqkv; N = 512; tc = 16; rowOff = 2048; }
  else if (id < 6144) { id -= 5120; src = Wv; dst = Wqkv; N = 512; tc = 16; rowOff = 2560; }
  else { id -= 6144; src = Wo; dst = WoT; N = 2048; tc = 64; rowOff = 0; }
  const int c0 = (id % tc) * 32, r0 = (id / tc) * 32;
  const int col = t & 31, rb = t >> 5;
#pragma unroll
  for (int i = 0; i < 4; i++)
    tile[rb + i * 8][col] = src[(size_t)(r0 + rb + i * 8) * N + c0 + col];
  __syncthreads();
#pragma unroll
  for (int i = 0; i < 4; i++)
    dst[(size_t)(rowOff + c0 + rb + i * 8) * 2048 + r0 + col] =
        f2b(tile[col][rb + i * 8]);
}

// ---------------------------------------------------------------------------
// bf16 MFMA GEMM (m97 structure + XCD-aware block swizzle T1):
// C(MxN) = A(MxK) @ Bt(NxK)^T. 128x128 tile, BK=32, 256 thr = 4 waves,
// global_load_lds staging. Grid must be divisible by 8 (768 and 512 here).
// ---------------------------------------------------------------------------
__global__ __launch_bounds__(256) void bgemm_kernel(
    const unsigned short* __restrict__ A, const unsigned short* __restrict__ Bt,
    void* __restrict__ C, int M, int N, int K, int bf16_out) {
  __shared__ unsigned short As[128 * 32];
  __shared__ unsigned short Bs[128 * 32];

  const int t = threadIdx.x;
  const int w = t >> 6, l = t & 63;
  const int quad = l >> 4, lx = l & 15;

  // T1 XCD swizzle (bijective: nwg % 8 == 0 for both call sites)
  const int nwg = gridDim.x * gridDim.y;
  const int orig = blockIdx.y * gridDim.x + blockIdx.x;
  const int swz = (orig & 7) * (nwg >> 3) + (orig >> 3);
  const int bx = swz % gridDim.x, by = swz / gridDim.x;
  const int row0 = by * 128, col0 = bx * 128;
  const int wr = (w >> 1) * 64, wc = (w & 1) * 64;

  f32x4 acc[4][4];
#pragma unroll
  for (int mt = 0; mt < 4; mt++)
#pragma unroll
    for (int nt = 0; nt < 4; nt++) acc[mt][nt] = (f32x4){0.f, 0.f, 0.f, 0.f};

  for (int kt = 0; kt < K; kt += 32) {
    __syncthreads();
#pragma unroll
    for (int j = 0; j < 2; j++) {
      int ch = w * 128 + j * 64 + l;
      int r = ch >> 2, kc = (ch & 3) * 8;
      gload_lds16(A + (size_t)(row0 + r) * K + kt + kc, &As[ch * 8]);
      gload_lds16(Bt + (size_t)(col0 + r) * K + kt + kc, &Bs[ch * 8]);
    }
    __syncthreads();

    bf16x8 af[4], bfr[4];
#pragma unroll
    for (int mt = 0; mt < 4; mt++)
      af[mt] = *(const bf16x8*)&As[(wr + mt * 16 + lx) * 32 + quad * 8];
#pragma unroll
    for (int nt = 0; nt < 4; nt++)
      bfr[nt] = *(const bf16x8*)&Bs[(wc + nt * 16 + lx) * 32 + quad * 8];
#pragma unroll
    for (int mt = 0; mt < 4; mt++)
#pragma unroll
      for (int nt = 0; nt < 4; nt++)
        acc[mt][nt] = __builtin_amdgcn_mfma_f32_16x16x32_bf16(af[mt], bfr[nt],
                                                              acc[mt][nt], 0, 0, 0);
  }

  if (bf16_out) {
    unsigned short* Cp = (unsigned short*)C;
#pragma unroll
    for (int mt = 0; mt < 4; mt++)
#pragma unroll
      for (int nt = 0; nt < 4; nt++)
#pragma unroll
        for (int r = 0; r < 4; r++) {
          int row = row0 + wr + mt * 16 + quad * 4 + r;
          int col = col0 + wc + nt * 16 + lx;
          Cp[(size_t)row * N + col] = f2b(acc[mt][nt][r]);
        }
  } else {
    float* Cp = (float*)C;
#pragma unroll
    for (int mt = 0; mt < 4; mt++)
#pragma unroll
      for (int nt = 0; nt < 4; nt++)
#pragma unroll
        for (int r = 0; r < 4; r++) {
          int row = row0 + wr + mt * 16 + quad * 4 + r;
          int col = col0 + wc + nt * 16 + lx;
          Cp[(size_t)row * N + col] = acc[mt][nt][r];
        }
  }
}

// ---------------------------------------------------------------------------
// Merged RoPE + V-transpose (independent column ranges of QKV; one launch).
// Blocks [0, 20480): RoPE in place on QKV (row stride 3072). Q cols [0,2048)
// get the combined scale log2(e)/sqrt(HD); K cols [2048,2560) unscaled.
// Blocks [20480, 22528): transpose V (cols [2560,3072)) -> Vt (512 x S).
// ---------------------------------------------------------------------------
__global__ __launch_bounds__(256) void ropev_kernel(
    unsigned short* __restrict__ QKV, unsigned short* __restrict__ Vt) {
  const int t = threadIdx.x;
  if (blockIdx.x < 20480) {
    int id = blockIdx.x * 256 + t;
    int d = id & 63;
    int rem = id >> 6;
    int head = rem % 20;
    int s = rem / 20;
    unsigned short* p;
    float scale;
    if (head < N_HEADS) {
      p = QKV + (size_t)s * QKV_N + head * HEAD_DIM;
      scale = 0.12753139187f;  // log2(e) / sqrt(128)
    } else {
      p = QKV + (size_t)s * QKV_N + 2048 + (head - N_HEADS) * HEAD_DIM;
      scale = 1.0f;
    }
    float inv = exp2f(-(float)d * (13.287712379549449f / 64.0f));
    float ang = (float)s * inv;
    float sn, c;
    sincosf(ang, &sn, &c);
    float xr = b2f(p[d]), xi = b2f(p[d + 64]);
    p[d] = f2b((xr * c - xi * sn) * scale);
    p[d + 64] = f2b((xr * sn + xi * c) * scale);
    return;
  }
  __shared__ unsigned short tile[32][33];
  const unsigned short* Vb = QKV + 2560;
  int id = blockIdx.x - 20480;
  const int c0 = (id & 15) * 32;   // 512/32 = 16 column tiles
  const int s0 = (id >> 4) * 32;
  const int col = t & 31, rbase = t >> 5;
#pragma unroll
  for (int i = 0; i < 4; i++) {
    int row = rbase + i * 8;
    tile[row][col] = Vb[(size_t)(s0 + row) * QKV_N + c0 + col];
  }
  __syncthreads();
#pragma unroll
  for (int i = 0; i < 4; i++) {
    int row = rbase + i * 8;
    Vt[(size_t)(c0 + row) * S_LEN + s0 + col] = tile[col][row];
  }
}

// ---------------------------------------------------------------------------
// Flash attention, transposed-score form, FIXED-SHIFT softmax.
// R7: XCD-aware block swizzle for K/V L2 residency. Default x-fastest
// dispatch round-robins the 32 qt-blocks of each head across all 8 XCDs ->
// per-XCD K/V working set = 4 kvh groups x 2MB = 8MB > 4MB L2 (staging
// loads hit LLC ~450cy). Bijective remap (512 = 8x64): XCD x gets flat ids
// [64x,64x+64) = heads [2x,2x+2) = ONE kvh group (2MB, L2-resident); both
// co-resident blocks/CU share kvh. Lower staging latency -> less idle at
// the top-of-tile vmcnt(4) wait.
// (R4 state otherwise: counted-vmcnt split waits, setprio, deferred l.)
// ---------------------------------------------------------------------------
__global__ __launch_bounds__(256, 2) void attn_kernel(
    const unsigned short* __restrict__ Qb, const unsigned short* __restrict__ Kb,
    const unsigned short* __restrict__ Vt, unsigned short* __restrict__ Ob) {
  __shared__ unsigned short Ks[2][64 * 128];   // [krow][d], chunk-swizzled
  __shared__ unsigned short Vs[2][128 * 64];   // [d][krow], chunk-swizzled
  __shared__ unsigned short Pt[4][32 * 64];    // per-wave P^T [q][k], swizzled

  const int t = threadIdx.x;
  const int wave = t >> 6;
  const int lane = t & 63;
  const int quad = lane >> 4;
  const int lx = lane & 15;
  const int lx7 = lx & 7;

  // T1 XCD swizzle: orig%8 (=XCD) owns contiguous swizzled ids -> one kvh/XCD
  const int orig = blockIdx.y * gridDim.x + blockIdx.x;  // grid (32,16) = 512
  const int swz = (orig & 7) * 64 + (orig >> 3);
  const int qt = swz & 31;   // 0..31
  const int h = swz >> 5;    // 0..15
  const int kvh = h >> 2;

  const unsigned short* Kg = Kb + kvh * HEAD_DIM;              // stride QKV_N
  const unsigned short* Vg = Vt + (size_t)(kvh * HEAD_DIM) * S_LEN;

  // Q fragments (whole kernel in registers): B-operand [n=lx][k=quad*8+j]
  const unsigned short* Qg =
      Qb + (size_t)(qt * 128 + wave * 32) * QKV_N + h * HEAD_DIM;
  bf16x8 qf[2][4];
#pragma unroll
  for (int qs = 0; qs < 2; qs++)
#pragma unroll
    for (int ks = 0; ks < 4; ks++)
      qf[qs][ks] = *(const bf16x8*)(Qg + (size_t)(qs * 16 + lx) * QKV_N +
                                    (quad << 3) + (ks << 5));

  f32x4 oacc[2][8];
#pragma unroll
  for (int qs = 0; qs < 2; qs++)
#pragma unroll
    for (int dt = 0; dt < 8; dt++) oacc[qs][dt] = (f32x4){0.f, 0.f, 0.f, 0.f};
  float l_st[2] = {0.f, 0.f};

  // K tile: 64 rows x 16 chunks; slot(r,c) holds global chunk (r, c^(r&7)).
  // V^T tile: 128 rows x 8 chunks; same self-inverse XOR swizzle.
  const unsigned short* kgp[4];
  const unsigned short* vgp[4];
#pragma unroll
  for (int j = 0; j < 4; j++) {
    int ch = (j * 4 + wave) * 64 + lane;
    int r = ch >> 4, c = ch & 15;
    kgp[j] = Kg + (size_t)r * QKV_N + ((c ^ (r & 7)) << 3);
    int d = ch >> 3, c2 = ch & 7;
    vgp[j] = Vg + (size_t)d * S_LEN + ((c2 ^ (d & 7)) << 3);
  }

  // K loads issued before V loads: top-of-tile vmcnt(4) = own K landed;
  // mid-tile vmcnt(8) = own V landed (next-tile prefetch stays in flight).
  auto stage = [&](int kt, int b) {
#pragma unroll
    for (int j = 0; j < 4; j++) {  // 4 * 4 waves * 64 lanes = 1024 chunks
      int ch = (j * 4 + wave) * 64 + lane;
      gload_lds16(kgp[j] + (size_t)kt * (64 * QKV_N), &Ks[b][ch * 8]);
    }
#pragma unroll
    for (int j = 0; j < 4; j++) {
      int ch = (j * 4 + wave) * 64 + lane;
      gload_lds16(vgp[j] + kt * 64, &Vs[b][ch * 8]);
    }
  };

  stage(0, 0);

  for (int kt = 0; kt < S_LEN / 64; kt++) {
    VMCNT(4);   // own K(kt) landed (V may still be in flight)
    SBAR();     // all waves' K(kt) visible
    if (kt + 1 < S_LEN / 64) stage(kt + 1, (kt + 1) & 1);  // prefetch overlap
    const unsigned short* KsC = Ks[kt & 1];
    const unsigned short* VsC = Vs[kt & 1];

    // ---- S^T = K @ Q^T fused with exp2/store; acc seeded with -SM_SHIFT so
    // no per-element subtract: k = ksub*16+quad*4+r, q = qs*16+lx
#pragma unroll
    for (int ksub = 0; ksub < 4; ksub++) {
      bf16x8 kf[4];
#pragma unroll
      for (int ks = 0; ks < 4; ks++)
        kf[ks] = *(const bf16x8*)&KsC[(ksub * 16 + lx) * 128 +
                                      (((ks * 4 + quad) ^ lx7) << 3)];
#pragma unroll
      for (int qs = 0; qs < 2; qs++) {
        f32x4 a = (f32x4){-SM_SHIFT, -SM_SHIFT, -SM_SHIFT, -SM_SHIFT};
        __builtin_amdgcn_s_setprio(1);
#pragma unroll
        for (int ks = 0; ks < 4; ks++)
          a = __builtin_amdgcn_mfma_f32_16x16x32_bf16(kf[ks], qf[qs][ks], a, 0, 0, 0);
        __builtin_amdgcn_s_setprio(0);
        float p0 = EXP2(a[0]);
        float p1 = EXP2(a[1]);
        float p2 = EXP2(a[2]);
        float p3 = EXP2(a[3]);
        l_st[qs] += (p0 + p1) + (p2 + p3);
        // P^T[q][k]: k = ksub*16+quad*4 (+r); chunk 2ksub+(quad>>1) ^ lx7
        *(uint2*)&Pt[wave][(qs * 16 + lx) * 64 +
                           (((2 * ksub + (quad >> 1)) ^ lx7) << 3) +
                           ((quad & 1) << 2)] =
            make_uint2(cvt_pk_bf16(p0, p1), cvt_pk_bf16(p2, p3));
      }
    }

    // ---- wait own V(kt) landed; next-tile prefetch (8 loads) stays live ----
    if (kt + 1 < S_LEN / 64) { VMCNT(8); } else { VMCNT(0); }
    SBAR();     // all waves' V(kt) visible

    // ---- O^T += V^T @ P^T (Pt wave-local: lgkm wait only) ----
#pragma unroll
    for (int st = 0; st < 2; st++) {
      const int pc = ((st * 4 + quad) ^ lx7) << 3;
      bf16x8 pb0 = *(const bf16x8*)&Pt[wave][lx * 64 + pc];
      bf16x8 pb1 = *(const bf16x8*)&Pt[wave][(16 + lx) * 64 + pc];
      __builtin_amdgcn_s_setprio(1);
#pragma unroll
      for (int dt = 0; dt < 8; dt++) {
        bf16x8 vf = *(const bf16x8*)&VsC[(dt * 16 + lx) * 64 + pc];
        oacc[0][dt] = __builtin_amdgcn_mfma_f32_16x16x32_bf16(vf, pb0, oacc[0][dt], 0, 0, 0);
        oacc[1][dt] = __builtin_amdgcn_mfma_f32_16x16x32_bf16(vf, pb1, oacc[1][dt], 0, 0, 0);
      }
      __builtin_amdgcn_s_setprio(0);
    }
  }

  // ---- epilogue: final cross-lane l reduce, O = (O^T)^T / l, 8B stores ----
#pragma unroll
  for (int qs = 0; qs < 2; qs++) {
    float l = l_st[qs];
    l += __shfl_xor(l, 16);
    l += __shfl_xor(l, 32);
    float linv = 1.0f / l;
    unsigned short* ob = Ob +
        (size_t)(qt * 128 + wave * 32 + qs * 16 + lx) * D_MODEL + h * HEAD_DIM +
        quad * 4;
#pragma unroll
    for (int dt = 0; dt < 8; dt++) {
      *(uint2*)&ob[dt * 16] = make_uint2(
          cvt_pk_bf16(oacc[qs][dt][0] * linv, oacc[qs][dt][1] * linv),
          cvt_pk_bf16(oacc[qs][dt][2] * linv, oacc[qs][dt][3] * linv));
    }
  }
}

// ---------------------------------------------------------------------------
extern "C" void kernel_launch(void* const* d_in, const int* in_sizes, int n_in,
                              void* d_out, int out_size, void* d_ws,
                              size_t ws_size, hipStream_t stream) {
  const float* X = (const float*)d_in[0];   // 4096 x 2048
  const float* Wq = (const float*)d_in[1];  // 2048 x 2048
  const float* Wk = (const float*)d_in[2];  // 2048 x 512
  const float* Wv = (const float*)d_in[3];  // 2048 x 512
  const float* Wo = (const float*)d_in[4];  // 2048 x 2048
  float* out = (float*)d_out;               // 4096 x 2048

  const size_t MB = 1048576;
  char* ws = (char*)d_ws;
  unsigned short* Xb    = (unsigned short*)ws;              // 16 MB
  unsigned short* WqkvT = (unsigned short*)(ws + 16 * MB);  // 12 MB [3072][2048]
  unsigned short* WoT   = (unsigned short*)(ws + 28 * MB);  //  8 MB
  unsigned short* QKV   = (unsigned short*)(ws + 36 * MB);  // 24 MB [4096][3072]
  unsigned short* Vtr   = (unsigned short*)(ws + 60 * MB);  //  4 MB [512][4096]
  unsigned short* Ob    = (unsigned short*)(ws + 64 * MB);  // 16 MB

  dim3 blk(256);
  // prep: X conversion + all 4 weight transposes in one launch
  prep_kernel<<<14336, blk, 0, stream>>>(X, Wq, Wk, Wv, Wo, Xb, WqkvT, WoT);
  // fused QKV projection: [4096][3072] bf16 (768 wgs, %8==0 for swizzle)
  bgemm_kernel<<<dim3(QKV_N / 128, S_LEN / 128), blk, 0, stream>>>(
      Xb, WqkvT, QKV, S_LEN, QKV_N, D_MODEL, 1);
  // RoPE on Q (log2e-scaled) and K + V transpose -> Vt, one launch
  ropev_kernel<<<20480 + 2048, blk, 0, stream>>>(QKV, Vtr);
  // attention (bf16 MFMA, 32 q/wave, fixed-shift softmax), bf16 O
  attn_kernel<<<dim3(S_LEN / 128, N_HEADS), blk, 0, stream>>>(
      QKV, QKV + 2048, Vtr, Ob);
  // output projection (fp32 out): 512 wgs, %8==0 for swizzle
  bgemm_kernel<<<dim3(D_MODEL / 128, S_LEN / 128), blk, 0, stream>>>(
      Ob, WoT, out, S_LEN, D_MODEL, D_MODEL, 0);
}

// Round 8
// 380.367 us; speedup vs baseline: 1.0800x; 1.0174x over previous
//
#include <hip/hip_runtime.h>
#include <math.h>

#define S_LEN 4096
#define D_MODEL 2048
#define N_HEADS 16
#define N_KV 4
#define HEAD_DIM 128
#define KV_D 512
#define QKV_N 3072   // fused QKV projection width; Q/K row stride
#define SM_SHIFT 18.0f  // fixed softmax shift (log2 domain); exact identity

typedef short bf16x8 __attribute__((ext_vector_type(8)));
typedef float f32x4 __attribute__((ext_vector_type(4)));

#if __has_builtin(__builtin_amdgcn_exp2f)
#define EXP2(x) __builtin_amdgcn_exp2f(x)
#else
#define EXP2(x) exp2f(x)
#endif

// raw barrier with compiler memory ordering (no implicit full waitcnt drain)
#define SBAR() asm volatile("s_barrier" ::: "memory")
#define VMCNT(n) asm volatile("s_waitcnt vmcnt(" #n ")" ::: "memory")

static __device__ __forceinline__ float b2f(unsigned short h) {
  return __uint_as_float(((unsigned int)h) << 16);
}
// HW packed f32->bf16 (RNE): lo half = cvt(a), hi half = cvt(b). 1 instr vs ~7.
static __device__ __forceinline__ unsigned int cvt_pk_bf16(float a, float b) {
  unsigned int r;
  asm("v_cvt_pk_bf16_f32 %0, %1, %2" : "=v"(r) : "v"(a), "v"(b));
  return r;
}
// scalar f32->bf16 via the same HW op (RNE; identical numerics to manual RNE)
static __device__ __forceinline__ unsigned short f2b(float f) {
  return (unsigned short)cvt_pk_bf16(f, f);
}

// async 16B global -> LDS (wave-uniform base + lane*16 ordering)
static __device__ __forceinline__ void gload_lds16(const unsigned short* g,
                                                   unsigned short* l) {
  __builtin_amdgcn_global_load_lds(
      (const __attribute__((address_space(1))) void*)g,
      (__attribute__((address_space(3))) void*)l, 16, 0, 0);
}

// ---------------------------------------------------------------------------
// prep: blocks [0,4096) convert X fp32->bf16; remaining blocks transpose the
// four weight matrices into bf16 W^T form (Wq/Wk/Wv stacked [3072][2048]).
// ---------------------------------------------------------------------------
__global__ __launch_bounds__(256) void prep_kernel(
    const float* __restrict__ X, const float* __restrict__ Wq,
    const float* __restrict__ Wk, const float* __restrict__ Wv,
    const float* __restrict__ Wo, unsigned short* __restrict__ Xb,
    unsigned short* __restrict__ Wqkv, unsigned short* __restrict__ WoT) {
  __shared__ float tile[32][33];
  const int b = blockIdx.x, t = threadIdx.x;
  if (b < 4096) {  // convx: 2048 elems per block
    int i = b * 2048 + t * 8;
    float4 a = *(const float4*)(X + i);
    float4 v = *(const float4*)(X + i + 4);
    unsigned int tmp[4] = {cvt_pk_bf16(a.x, a.y), cvt_pk_bf16(a.z, a.w),
                           cvt_pk_bf16(v.x, v.y), cvt_pk_bf16(v.z, v.w)};
    *(uint4*)&Xb[i] = *(uint4*)tmp;
    return;
  }
  int id = b - 4096;
  const float* src;
  unsigned short* dst;
  int N, tc, rowOff;
  if (id < 4096) { src = Wq; dst = Wqkv; N = 2048; tc = 64; rowOff = 0; }
  else if (id < 5120) { id -= 4096; src = Wk; dst = Wqkv; N = 512; tc = 16; rowOff = 2048; }
  else if (id < 6144) { id -= 5120; src = Wv; dst = Wqkv; N = 512; tc = 16; rowOff = 2560; }
  else { id -= 6144; src = Wo; dst = WoT; N = 2048; tc = 64; rowOff = 0; }
  const int c0 = (id % tc) * 32, r0 = (id / tc) * 32;
  const int col = t & 31, rb = t >> 5;
#pragma unroll
  for (int i = 0; i < 4; i++)
    tile[rb + i * 8][col] = src[(size_t)(r0 + rb + i * 8) * N + c0 + col];
  __syncthreads();
#pragma unroll
  for (int i = 0; i < 4; i++)
    dst[(size_t)(rowOff + c0 + rb + i * 8) * 2048 + r0 + col] =
        f2b(tile[col][rb + i * 8]);
}

// ---------------------------------------------------------------------------
// bf16 MFMA GEMM (m97 structure + XCD-aware block swizzle T1):
// C(MxN) = A(MxK) @ Bt(NxK)^T. 128x128 tile, BK=32, 256 thr = 4 waves,
// global_load_lds staging. Grid must be divisible by 8 (768 and 512 here).
// ---------------------------------------------------------------------------
__global__ __launch_bounds__(256) void bgemm_kernel(
    const unsigned short* __restrict__ A, const unsigned short* __restrict__ Bt,
    void* __restrict__ C, int M, int N, int K, int bf16_out) {
  __shared__ unsigned short As[128 * 32];
  __shared__ unsigned short Bs[128 * 32];

  const int t = threadIdx.x;
  const int w = t >> 6, l = t & 63;
  const int quad = l >> 4, lx = l & 15;

  // T1 XCD swizzle (bijective: nwg % 8 == 0 for both call sites)
  const int nwg = gridDim.x * gridDim.y;
  const int orig = blockIdx.y * gridDim.x + blockIdx.x;
  const int swz = (orig & 7) * (nwg >> 3) + (orig >> 3);
  const int bx = swz % gridDim.x, by = swz / gridDim.x;
  const int row0 = by * 128, col0 = bx * 128;
  const int wr = (w >> 1) * 64, wc = (w & 1) * 64;

  f32x4 acc[4][4];
#pragma unroll
  for (int mt = 0; mt < 4; mt++)
#pragma unroll
    for (int nt = 0; nt < 4; nt++) acc[mt][nt] = (f32x4){0.f, 0.f, 0.f, 0.f};

  for (int kt = 0; kt < K; kt += 32) {
    __syncthreads();
#pragma unroll
    for (int j = 0; j < 2; j++) {
      int ch = w * 128 + j * 64 + l;
      int r = ch >> 2, kc = (ch & 3) * 8;
      gload_lds16(A + (size_t)(row0 + r) * K + kt + kc, &As[ch * 8]);
      gload_lds16(Bt + (size_t)(col0 + r) * K + kt + kc, &Bs[ch * 8]);
    }
    __syncthreads();

    bf16x8 af[4], bfr[4];
#pragma unroll
    for (int mt = 0; mt < 4; mt++)
      af[mt] = *(const bf16x8*)&As[(wr + mt * 16 + lx) * 32 + quad * 8];
#pragma unroll
    for (int nt = 0; nt < 4; nt++)
      bfr[nt] = *(const bf16x8*)&Bs[(wc + nt * 16 + lx) * 32 + quad * 8];
#pragma unroll
    for (int mt = 0; mt < 4; mt++)
#pragma unroll
      for (int nt = 0; nt < 4; nt++)
        acc[mt][nt] = __builtin_amdgcn_mfma_f32_16x16x32_bf16(af[mt], bfr[nt],
                                                              acc[mt][nt], 0, 0, 0);
  }

  if (bf16_out) {
    unsigned short* Cp = (unsigned short*)C;
#pragma unroll
    for (int mt = 0; mt < 4; mt++)
#pragma unroll
      for (int nt = 0; nt < 4; nt++)
#pragma unroll
        for (int r = 0; r < 4; r++) {
          int row = row0 + wr + mt * 16 + quad * 4 + r;
          int col = col0 + wc + nt * 16 + lx;
          Cp[(size_t)row * N + col] = f2b(acc[mt][nt][r]);
        }
  } else {
    float* Cp = (float*)C;
#pragma unroll
    for (int mt = 0; mt < 4; mt++)
#pragma unroll
      for (int nt = 0; nt < 4; nt++)
#pragma unroll
        for (int r = 0; r < 4; r++) {
          int row = row0 + wr + mt * 16 + quad * 4 + r;
          int col = col0 + wc + nt * 16 + lx;
          Cp[(size_t)row * N + col] = acc[mt][nt][r];
        }
  }
}

// ---------------------------------------------------------------------------
// Merged RoPE + V-transpose (independent column ranges of QKV; one launch).
// Blocks [0, 20480): RoPE in place on QKV (row stride 3072). Q cols [0,2048)
// get the combined scale log2(e)/sqrt(HD); K cols [2048,2560) unscaled.
// Blocks [20480, 22528): transpose V (cols [2560,3072)) -> Vt (512 x S).
// ---------------------------------------------------------------------------
__global__ __launch_bounds__(256) void ropev_kernel(
    unsigned short* __restrict__ QKV, unsigned short* __restrict__ Vt) {
  const int t = threadIdx.x;
  if (blockIdx.x < 20480) {
    int id = blockIdx.x * 256 + t;
    int d = id & 63;
    int rem = id >> 6;
    int head = rem % 20;
    int s = rem / 20;
    unsigned short* p;
    float scale;
    if (head < N_HEADS) {
      p = QKV + (size_t)s * QKV_N + head * HEAD_DIM;
      scale = 0.12753139187f;  // log2(e) / sqrt(128)
    } else {
      p = QKV + (size_t)s * QKV_N + 2048 + (head - N_HEADS) * HEAD_DIM;
      scale = 1.0f;
    }
    float inv = exp2f(-(float)d * (13.287712379549449f / 64.0f));
    float ang = (float)s * inv;
    float sn, c;
    sincosf(ang, &sn, &c);
    float xr = b2f(p[d]), xi = b2f(p[d + 64]);
    p[d] = f2b((xr * c - xi * sn) * scale);
    p[d + 64] = f2b((xr * sn + xi * c) * scale);
    return;
  }
  __shared__ unsigned short tile[32][33];
  const unsigned short* Vb = QKV + 2560;
  int id = blockIdx.x - 20480;
  const int c0 = (id & 15) * 32;   // 512/32 = 16 column tiles
  const int s0 = (id >> 4) * 32;
  const int col = t & 31, rbase = t >> 5;
#pragma unroll
  for (int i = 0; i < 4; i++) {
    int row = rbase + i * 8;
    tile[row][col] = Vb[(size_t)(s0 + row) * QKV_N + c0 + col];
  }
  __syncthreads();
#pragma unroll
  for (int i = 0; i < 4; i++) {
    int row = rbase + i * 8;
    Vt[(size_t)(c0 + row) * S_LEN + s0 + col] = tile[col][row];
  }
}

// ---------------------------------------------------------------------------
// Flash attention, transposed-score form, FIXED-SHIFT softmax.
// R8: occupancy via single-buffered K/V. R7 data: VGPR now 88 (was 112 at
// R2's failed occupancy attack), so the register tier allows 3 waves/SIMD
// (~170 regs/wave >= 88+64 acc worst case); LDS was the binding constraint
// (80KB -> 2 blocks). Dropping BOTH K and V double-buffers (tiles stay
// 64-wide: swizzle depth and bank-conflict count unchanged, avoiding R2's
// conflict regression): Ks 16 + Vs 16 + Pt 16 = 48KB -> 3 blocks/CU.
// 3-barrier schedule with verified counted waits:
//   top:  vmcnt(4) [own K landed; V in flight] + SBAR -> QK
//   mid:  vmcnt(0) [V landed; issued a full phase ago, L2-resident ~200cy]
//         + SBAR [V visible AND all Ks reads retired] -> stage K(kt+1)
//         [hides under PV ~256cy] -> PV
//   post: SBAR [all Vs reads retired] -> stage V(kt+1) [hides under next
//         QK ~400cy] -> outstanding K4+V4=8 at next top (uniform vmcnt(4)).
// ---------------------------------------------------------------------------
__global__ __launch_bounds__(256, 3) void attn_kernel(
    const unsigned short* __restrict__ Qb, const unsigned short* __restrict__ Kb,
    const unsigned short* __restrict__ Vt, unsigned short* __restrict__ Ob) {
  __shared__ unsigned short Ks[64 * 128];   // [krow][d], chunk-swizzled
  __shared__ unsigned short Vs[128 * 64];   // [d][krow], chunk-swizzled
  __shared__ unsigned short Pt[4][32 * 64]; // per-wave P^T [q][k], swizzled

  const int t = threadIdx.x;
  const int wave = t >> 6;
  const int lane = t & 63;
  const int quad = lane >> 4;
  const int lx = lane & 15;
  const int lx7 = lx & 7;

  // T1 XCD swizzle: orig%8 (=XCD) owns contiguous swizzled ids -> one kvh/XCD
  const int orig = blockIdx.y * gridDim.x + blockIdx.x;  // grid (32,16) = 512
  const int swz = (orig & 7) * 64 + (orig >> 3);
  const int qt = swz & 31;   // 0..31
  const int h = swz >> 5;    // 0..15
  const int kvh = h >> 2;

  const unsigned short* Kg = Kb + kvh * HEAD_DIM;              // stride QKV_N
  const unsigned short* Vg = Vt + (size_t)(kvh * HEAD_DIM) * S_LEN;

  // Q fragments (whole kernel in registers): B-operand [n=lx][k=quad*8+j]
  const unsigned short* Qg =
      Qb + (size_t)(qt * 128 + wave * 32) * QKV_N + h * HEAD_DIM;
  bf16x8 qf[2][4];
#pragma unroll
  for (int qs = 0; qs < 2; qs++)
#pragma unroll
    for (int ks = 0; ks < 4; ks++)
      qf[qs][ks] = *(const bf16x8*)(Qg + (size_t)(qs * 16 + lx) * QKV_N +
                                    (quad << 3) + (ks << 5));

  f32x4 oacc[2][8];
#pragma unroll
  for (int qs = 0; qs < 2; qs++)
#pragma unroll
    for (int dt = 0; dt < 8; dt++) oacc[qs][dt] = (f32x4){0.f, 0.f, 0.f, 0.f};
  float l_st[2] = {0.f, 0.f};

  // K tile: 64 rows x 16 chunks; slot(r,c) holds global chunk (r, c^(r&7)).
  // V^T tile: 128 rows x 8 chunks; same self-inverse XOR swizzle.
  const unsigned short* kgp[4];
  const unsigned short* vgp[4];
#pragma unroll
  for (int j = 0; j < 4; j++) {
    int ch = (j * 4 + wave) * 64 + lane;
    int r = ch >> 4, c = ch & 15;
    kgp[j] = Kg + (size_t)r * QKV_N + ((c ^ (r & 7)) << 3);
    int d = ch >> 3, c2 = ch & 7;
    vgp[j] = Vg + (size_t)d * S_LEN + ((c2 ^ (d & 7)) << 3);
  }

  auto stageK = [&](int kt) {
#pragma unroll
    for (int j = 0; j < 4; j++) {  // 4 * 4 waves * 64 lanes = 1024 chunks
      int ch = (j * 4 + wave) * 64 + lane;
      gload_lds16(kgp[j] + (size_t)kt * (64 * QKV_N), &Ks[ch * 8]);
    }
  };
  auto stageV = [&](int kt) {
#pragma unroll
    for (int j = 0; j < 4; j++) {
      int ch = (j * 4 + wave) * 64 + lane;
      gload_lds16(vgp[j] + kt * 64, &Vs[ch * 8]);
    }
  };

  stageK(0);
  stageV(0);

  for (int kt = 0; kt < S_LEN / 64; kt++) {
    VMCNT(4);   // own K(kt) landed (V(kt) may still be in flight)
    SBAR();     // all waves' K(kt) visible

    // ---- S^T = K @ Q^T fused with exp2/store; acc seeded with -SM_SHIFT so
    // no per-element subtract: k = ksub*16+quad*4+r, q = qs*16+lx
#pragma unroll
    for (int ksub = 0; ksub < 4; ksub++) {
      bf16x8 kf[4];
#pragma unroll
      for (int ks = 0; ks < 4; ks++)
        kf[ks] = *(const bf16x8*)&Ks[(ksub * 16 + lx) * 128 +
                                     (((ks * 4 + quad) ^ lx7) << 3)];
#pragma unroll
      for (int qs = 0; qs < 2; qs++) {
        f32x4 a = (f32x4){-SM_SHIFT, -SM_SHIFT, -SM_SHIFT, -SM_SHIFT};
        __builtin_amdgcn_s_setprio(1);
#pragma unroll
        for (int ks = 0; ks < 4; ks++)
          a = __builtin_amdgcn_mfma_f32_16x16x32_bf16(kf[ks], qf[qs][ks], a, 0, 0, 0);
        __builtin_amdgcn_s_setprio(0);
        float p0 = EXP2(a[0]);
        float p1 = EXP2(a[1]);
        float p2 = EXP2(a[2]);
        float p3 = EXP2(a[3]);
        l_st[qs] += (p0 + p1) + (p2 + p3);
        // P^T[q][k]: k = ksub*16+quad*4 (+r); chunk 2ksub+(quad>>1) ^ lx7
        *(uint2*)&Pt[wave][(qs * 16 + lx) * 64 +
                           (((2 * ksub + (quad >> 1)) ^ lx7) << 3) +
                           ((quad & 1) << 2)] =
            make_uint2(cvt_pk_bf16(p0, p1), cvt_pk_bf16(p2, p3));
      }
    }

    // ---- V(kt) visible + all waves' Ks reads retired -> K buffer free ----
    VMCNT(0);
    SBAR();
    if (kt + 1 < S_LEN / 64) stageK(kt + 1);  // hides under PV

    // ---- O^T += V^T @ P^T (Pt wave-local: lgkm wait only) ----
#pragma unroll
    for (int st = 0; st < 2; st++) {
      const int pc = ((st * 4 + quad) ^ lx7) << 3;
      bf16x8 pb0 = *(const bf16x8*)&Pt[wave][lx * 64 + pc];
      bf16x8 pb1 = *(const bf16x8*)&Pt[wave][(16 + lx) * 64 + pc];
      __builtin_amdgcn_s_setprio(1);
#pragma unroll
      for (int dt = 0; dt < 8; dt++) {
        bf16x8 vf = *(const bf16x8*)&Vs[(dt * 16 + lx) * 64 + pc];
        oacc[0][dt] = __builtin_amdgcn_mfma_f32_16x16x32_bf16(vf, pb0, oacc[0][dt], 0, 0, 0);
        oacc[1][dt] = __builtin_amdgcn_mfma_f32_16x16x32_bf16(vf, pb1, oacc[1][dt], 0, 0, 0);
      }
      __builtin_amdgcn_s_setprio(0);
    }

    // ---- all waves' Vs reads retired -> V buffer free ----
    SBAR();
    if (kt + 1 < S_LEN / 64) stageV(kt + 1);  // hides under next QK
  }

  // ---- epilogue: final cross-lane l reduce, O = (O^T)^T / l, 8B stores ----
#pragma unroll
  for (int qs = 0; qs < 2; qs++) {
    float l = l_st[qs];
    l += __shfl_xor(l, 16);
    l += __shfl_xor(l, 32);
    float linv = 1.0f / l;
    unsigned short* ob = Ob +
        (size_t)(qt * 128 + wave * 32 + qs * 16 + lx) * D_MODEL + h * HEAD_DIM +
        quad * 4;
#pragma unroll
    for (int dt = 0; dt < 8; dt++) {
      *(uint2*)&ob[dt * 16] = make_uint2(
          cvt_pk_bf16(oacc[qs][dt][0] * linv, oacc[qs][dt][1] * linv),
          cvt_pk_bf16(oacc[qs][dt][2] * linv, oacc[qs][dt][3] * linv));
    }
  }
}

// ---------------------------------------------------------------------------
extern "C" void kernel_launch(void* const* d_in, const int* in_sizes, int n_in,
                              void* d_out, int out_size, void* d_ws,
                              size_t ws_size, hipStream_t stream) {
  const float* X = (const float*)d_in[0];   // 4096 x 2048
  const float* Wq = (const float*)d_in[1];  // 2048 x 2048
  const float* Wk = (const float*)d_in[2];  // 2048 x 512
  const float* Wv = (const float*)d_in[3];  // 2048 x 512
  const float* Wo = (const float*)d_in[4];  // 2048 x 2048
  float* out = (float*)d_out;               // 4096 x 2048

  const size_t MB = 1048576;
  char* ws = (char*)d_ws;
  unsigned short* Xb    = (unsigned short*)ws;              // 16 MB
  unsigned short* WqkvT = (unsigned short*)(ws + 16 * MB);  // 12 MB [3072][2048]
  unsigned short* WoT   = (unsigned short*)(ws + 28 * MB);  //  8 MB
  unsigned short* QKV   = (unsigned short*)(ws + 36 * MB);  // 24 MB [4096][3072]
  unsigned short* Vtr   = (unsigned short*)(ws + 60 * MB);  //  4 MB [512][4096]
  unsigned short* Ob    = (unsigned short*)(ws + 64 * MB);  // 16 MB

  dim3 blk(256);
  // prep: X conversion + all 4 weight transposes in one launch
  prep_kernel<<<14336, blk, 0, stream>>>(X, Wq, Wk, Wv, Wo, Xb, WqkvT, WoT);
  // fused QKV projection: [4096][3072] bf16 (768 wgs, %8==0 for swizzle)
  bgemm_kernel<<<dim3(QKV_N / 128, S_LEN / 128), blk, 0, stream>>>(
      Xb, WqkvT, QKV, S_LEN, QKV_N, D_MODEL, 1);
  // RoPE on Q (log2e-scaled) and K + V transpose -> Vt, one launch
  ropev_kernel<<<20480 + 2048, blk, 0, stream>>>(QKV, Vtr);
  // attention (bf16 MFMA, 32 q/wave, fixed-shift softmax), bf16 O
  attn_kernel<<<dim3(S_LEN / 128, N_HEADS), blk, 0, stream>>>(
      QKV, QKV + 2048, Vtr, Ob);
  // output projection (fp32 out): 512 wgs, %8==0 for swizzle
  bgemm_kernel<<<dim3(D_MODEL / 128, S_LEN / 128), blk, 0, stream>>>(
      Ob, WoT, out, S_LEN, D_MODEL, D_MODEL, 0);
}